// Round 1
// baseline (2718.601 us; speedup 1.0000x reference)
//
#include <hip/hip_runtime.h>
#include <cstdint>
#include <cstddef>

#define NBLK 64
#define NTHR 256

struct Ctl {
  int row; int i0; int used_cnt; int done; int pad0[12];   // 64B
  int bar_cnt; int pad1[15];                                // 64B
  int bar_gen; int pad2[15];                                // 64B
};

// IoU exactly as reference _box_iou, all f32 IEEE ops, no FMA-contractable exprs.
__device__ __forceinline__ float iou_f32(float4 p, float4 t, float area_t) {
  float area1 = (p.z - p.x) * (p.w - p.y);
  float ltx = fmaxf(p.x, t.x);
  float lty = fmaxf(p.y, t.y);
  float rbx = fminf(p.z, t.z);
  float rby = fminf(p.w, t.w);
  float wx = fmaxf(rbx - ltx, 0.0f);
  float wy = fmaxf(rby - lty, 0.0f);
  float inter = wx * wy;
  return inter / (area1 + area_t - inter);
}

__global__ void init_kernel(double* u, double* v, int* p, int* uep, int* ulist,
                            Ctl* ctl, int M, int NROWS) {
  int gid = blockIdx.x * blockDim.x + threadIdx.x;
  int stride = gridDim.x * blockDim.x;
  for (int j = gid; j <= M; j += stride) {
    v[j] = 0.0;
    uep[j] = 0;
    if (j >= 1) p[j] = 0;
  }
  for (int r = gid; r <= NROWS; r += stride) u[r] = 0.0;
  if (gid == 0) {
    p[0] = 1;            // reference: p[0] = i at row start
    ulist[0] = 0;        // used list always starts with column 0
    ctl->row = 1; ctl->i0 = 1; ctl->used_cnt = 1; ctl->done = 0;
    ctl->bar_cnt = 0; ctl->bar_gen = 0;
  }
}

__global__ void hung_kernel(const float4* __restrict__ pbox, const float4* __restrict__ tbox,
                            double* u, double* v, int* p, int* uep, int* ulist,
                            double* bval, int* bidxA, Ctl* ctl, int M, int NROWS) {
  const int tid = threadIdx.x;
  const int bx  = blockIdx.x;
  const int nb  = gridDim.x;
  const int gid = bx * blockDim.x + tid;
  const int stride = nb * blockDim.x;
  __shared__ double wval[NTHR / 64];
  __shared__ int    widx[NTHR / 64];
  int mygen = 0;

  for (;;) {
    const int row = ctl->row;
    const int i0  = ctl->i0;
    const float4 tb = tbox[i0 - 1];
    const float area_t = (tb.z - tb.x) * (tb.w - tb.y);
    const double u_i0 = u[i0];

    // scan all columns j=1..M, skip ones visited this row (uep[j]==row)
    double best = 1e300;
    int bj = 0x7fffffff;
    for (int j = 1 + gid; j <= M; j += stride) {
      if (uep[j] == row) continue;
      float io = iou_f32(pbox[j - 1], tb, area_t);
      double cur = (-(double)io - u_i0) - v[j];   // exact reference op order (f64)
      if (cur < best) { best = cur; bj = j; }     // ascending j -> first-index tie kept
    }
    // wave reduce (64 lanes), tie-break by smaller index
    for (int off = 32; off > 0; off >>= 1) {
      double ov = __shfl_down(best, off);
      int    oj = __shfl_down(bj, off);
      if (ov < best || (ov == best && oj < bj)) { best = ov; bj = oj; }
    }
    int wave = tid >> 6, lane = tid & 63;
    if (lane == 0) { wval[wave] = best; widx[wave] = bj; }
    __syncthreads();

    if (tid == 0) {
      for (int w = 1; w < NTHR / 64; ++w) {
        double ov = wval[w]; int oj = widx[w];
        if (ov < wval[0] || (ov == wval[0] && oj < widx[0])) { wval[0] = ov; widx[0] = oj; }
      }
      bval[bx] = wval[0]; bidxA[bx] = widx[0];
      __threadfence();
      int arrived = __hip_atomic_fetch_add(&ctl->bar_cnt, 1, __ATOMIC_ACQ_REL, __HIP_MEMORY_SCOPE_AGENT);
      if (arrived == nb - 1) {
        // I'm the reducer (last arriver)
        ctl->bar_cnt = 0;
        __threadfence();                      // acquire: see other blocks' bval/bidx, fresh u/v/p
        double d = 1e300; int j1 = 0x7fffffff;
        for (int b = 0; b < nb; ++b) {
          double ov = bval[b]; int oj = bidxA[b];
          if (ov < d || (ov == d && oj < j1)) { d = ov; j1 = oj; }
        }
        // u[p[used]] += delta ; v[used] -= delta   (used list in ascending-time order, entries distinct)
        int cnt = ctl->used_cnt;
        for (int k = 0; k < cnt; ++k) {
          int uc = ulist[k];
          u[p[uc]] += d;
          v[uc]    -= d;
        }
        int pj1 = p[j1];
        if (pj1 == 0) {
          p[j1] = row;                        // augmentation collapses (way==0) to this single write
          if (row == NROWS) {
            ctl->done = 1;
          } else {
            ctl->row = row + 1; ctl->i0 = row + 1; ctl->used_cnt = 1;
            p[0] = row + 1;
          }
        } else {
          uep[j1] = row;                      // mark visited this row
          ulist[cnt] = j1;
          ctl->used_cnt = cnt + 1;
          ctl->i0 = pj1;                      // chain to owner row
        }
        __threadfence();                      // release
        __hip_atomic_fetch_add(&ctl->bar_gen, 1, __ATOMIC_RELEASE, __HIP_MEMORY_SCOPE_AGENT);
      } else {
        while (__hip_atomic_load(&ctl->bar_gen, __ATOMIC_ACQUIRE, __HIP_MEMORY_SCOPE_AGENT) == mygen) {
          __builtin_amdgcn_s_sleep(1);
        }
      }
      __threadfence();                        // invalidate L1 before the block proceeds
    }
    __syncthreads();
    ++mygen;
    if (ctl->done) break;
  }
}

__global__ void loss_kernel(const float4* __restrict__ pbox, const float* __restrict__ confs,
                            const float4* __restrict__ tbox, const int* __restrict__ tlab,
                            const int* __restrict__ p, int* pairs, float* out,
                            int M, int NROWS, int C) {
  const int tid = threadIdx.x;
  for (int j = 1 + tid; j <= M; j += blockDim.x) {
    int pi = p[j];
    if (pi > 0) pairs[pi - 1] = j - 1;   // slot per target -> deterministic layout
  }
  __syncthreads();
  __shared__ float s_reg[NTHR];
  __shared__ float s_cls[NTHR];
  __shared__ int   s_acc[NTHR];
  float reg = 0.0f, cls = 0.0f; int acc = 0;
  if (tid < NROWS) {
    int pred = pairs[tid];
    float4 pb = pbox[pred];
    float4 tb = tbox[tid];
    float d0 = pb.x - tb.x, d1 = pb.y - tb.y, d2 = pb.z - tb.z, d3 = pb.w - tb.w;
    float a0 = fabsf(d0), a1 = fabsf(d1), a2 = fabsf(d2), a3 = fabsf(d3);
    float s = 0.0f;
    s += (a0 < 1.0f) ? 0.5f * d0 * d0 : a0 - 0.5f;
    s += (a1 < 1.0f) ? 0.5f * d1 * d1 : a1 - 0.5f;
    s += (a2 < 1.0f) ? 0.5f * d2 * d2 : a2 - 0.5f;
    s += (a3 < 1.0f) ? 0.5f * d3 * d3 : a3 - 0.5f;
    reg = s * 0.25f;                      // mean over 4

    const float* lg = confs + (long long)pred * C;
    float mx = lg[0]; int am = 0;
    for (int k = 1; k < C; ++k) { float x = lg[k]; if (x > mx) { mx = x; am = k; } }
    double se = 0.0;
    for (int k = 0; k < C; ++k) se += exp((double)(lg[k] - mx));
    int lab = tlab[tid];
    double logp = (double)(lg[lab] - mx) - log(se);
    cls = (float)(-logp);
    acc = (am == lab) ? 1 : 0;
  }
  s_reg[tid] = reg; s_cls[tid] = cls; s_acc[tid] = acc;
  __syncthreads();
  for (int s2 = NTHR / 2; s2 > 0; s2 >>= 1) {
    if (tid < s2) {
      s_reg[tid] += s_reg[tid + s2];
      s_cls[tid] += s_cls[tid + s2];
      s_acc[tid] += s_acc[tid + s2];
    }
    __syncthreads();
  }
  if (tid == 0) {
    out[0] = s_reg[0] + s_cls[0];
    out[1] = (float)s_acc[0];
  }
}

extern "C" void kernel_launch(void* const* d_in, const int* in_sizes, int n_in,
                              void* d_out, int out_size, void* d_ws, size_t ws_size,
                              hipStream_t stream) {
  const float4* pbox  = (const float4*)d_in[0];
  const float*  confs = (const float*)d_in[1];
  const float4* tbox  = (const float4*)d_in[2];
  const int*    tlab  = (const int*)d_in[3];

  int N = in_sizes[0] / 4;          // 100000 predictions
  int C = in_sizes[1] / N;          // 81 classes
  int NROWS = in_sizes[2] / 4;      // 128 targets
  int M = N;                        // columns = predictions

  char* w = (char*)d_ws;
  auto alloc = [&](size_t sz) { char* r = w; w += (sz + 255) & ~(size_t)255; return r; };
  Ctl*    ctl   = (Ctl*)   alloc(sizeof(Ctl));
  double* u     = (double*)alloc((size_t)(NROWS + 2) * sizeof(double));
  double* v     = (double*)alloc((size_t)(M + 2) * sizeof(double));
  int*    p     = (int*)   alloc((size_t)(M + 2) * sizeof(int));
  int*    uep   = (int*)   alloc((size_t)(M + 2) * sizeof(int));
  int*    ulist = (int*)   alloc((size_t)(NROWS + 8) * sizeof(int));
  double* bval  = (double*)alloc((size_t)NBLK * sizeof(double));
  int*    bidxA = (int*)   alloc((size_t)NBLK * sizeof(int));
  int*    pairs = (int*)   alloc((size_t)(NROWS + 8) * sizeof(int));

  init_kernel<<<128, 256, 0, stream>>>(u, v, p, uep, ulist, ctl, M, NROWS);

  void* args[] = { (void*)&pbox, (void*)&tbox, (void*)&u, (void*)&v, (void*)&p,
                   (void*)&uep, (void*)&ulist, (void*)&bval, (void*)&bidxA,
                   (void*)&ctl, (void*)&M, (void*)&NROWS };
  hipLaunchCooperativeKernel((const void*)hung_kernel, dim3(NBLK), dim3(NTHR), args, 0, stream);

  loss_kernel<<<1, NTHR, 0, stream>>>(pbox, confs, tbox, tlab, p, pairs, (float*)d_out, M, NROWS, C);
}

// Round 2
// 1097.938 us; speedup vs baseline: 2.4761x; 2.4761x over previous
//
#include <hip/hip_runtime.h>
#include <cstdint>
#include <cstddef>

#define NTHR_A 256
#define TOPK 64
#define TPT 16          // per-thread candidates in kernel A

// IoU exactly as reference _box_iou, all f32 IEEE ops (matches XLA/np bit-for-bit per round-1 absmax=0).
__device__ __forceinline__ float iou_f32(float4 p, float4 t, float area_t) {
  float area1 = (p.z - p.x) * (p.w - p.y);
  float ltx = fmaxf(p.x, t.x);
  float lty = fmaxf(p.y, t.y);
  float rbx = fminf(p.z, t.z);
  float rby = fminf(p.w, t.w);
  float wx = fmaxf(rbx - ltx, 0.0f);
  float wy = fmaxf(rby - lty, 0.0f);
  float inter = wx * wy;
  return inter / (area1 + area_t - inter);
}

// Kernel A: zero matcher state + per-row top-64 IoU candidates (exact (iou desc, idx asc) order).
__global__ void select_kernel(const float4* __restrict__ pbox, const float4* __restrict__ tbox,
                              double* __restrict__ v, int* __restrict__ p, int* __restrict__ uep,
                              int* __restrict__ intouch,
                              float* __restrict__ cand_iou, int* __restrict__ cand_idx,
                              int M, int NROWS) {
  const int tid = threadIdx.x;
  const int r   = blockIdx.x;
  const int gid = r * NTHR_A + tid;
  const int gstride = gridDim.x * NTHR_A;
  for (int j = gid; j <= M + 1; j += gstride) {
    v[j] = 0.0; p[j] = 0; uep[j] = 0; intouch[j] = 0;
  }
  if (r >= NROWS) return;

  const float4 tb = tbox[r];
  const float area_t = (tb.z - tb.x) * (tb.w - tb.y);

  // per-thread top-TPT, sorted (iou desc, idx asc), static indices -> registers
  float tv[TPT]; int ti[TPT];
#pragma unroll
  for (int k = 0; k < TPT; ++k) { tv[k] = -1.0f; ti[k] = 0x7fffffff; }
  for (int j0 = tid; j0 < M; j0 += NTHR_A) {
    float io = iou_f32(pbox[j0], tb, area_t);
    if (io > tv[TPT - 1]) {            // equal-to-min dropped: stable (existing has smaller idx)
      tv[TPT - 1] = io; ti[TPT - 1] = j0 + 1;
#pragma unroll
      for (int k = TPT - 1; k >= 1; --k) {
        bool sw = (tv[k] > tv[k - 1]) || (tv[k] == tv[k - 1] && ti[k] < ti[k - 1]);
        if (sw) {
          float t1 = tv[k]; tv[k] = tv[k - 1]; tv[k - 1] = t1;
          int   t2 = ti[k]; ti[k] = ti[k - 1]; ti[k - 1] = t2;
        }
      }
    }
  }

  __shared__ float lv[NTHR_A * TPT];   // 16KB
  __shared__ int   li[NTHR_A * TPT];   // 16KB
  __shared__ float s_wv[4]; __shared__ int s_wi[4]; __shared__ int s_wt[4];
  __shared__ int   s_wtid;
  __shared__ float s_ov[TOPK]; __shared__ int s_oi[TOPK];
#pragma unroll
  for (int k = 0; k < TPT; ++k) { lv[tid * TPT + k] = tv[k]; li[tid * TPT + k] = ti[k]; }
  __syncthreads();

  int h = 0;  // head into my sorted list
  for (int round = 0; round < TOPK; ++round) {
    float mv; int mi;
    if (h < TPT) { mv = lv[tid * TPT + h]; mi = li[tid * TPT + h]; }
    else         { mv = -2.0f; mi = 0x7fffffff; }
    int mt = tid;
    for (int off = 32; off; off >>= 1) {
      float ov = __shfl_down(mv, off); int oi = __shfl_down(mi, off); int ot = __shfl_down(mt, off);
      bool b = (ov > mv) || (ov == mv && oi < mi);
      if (b) { mv = ov; mi = oi; mt = ot; }
    }
    if ((tid & 63) == 0) { int w = tid >> 6; s_wv[w] = mv; s_wi[w] = mi; s_wt[w] = mt; }
    __syncthreads();
    if (tid == 0) {
      float bv = s_wv[0]; int bi = s_wi[0]; int bt = s_wt[0];
      for (int w = 1; w < 4; ++w) {
        bool b = (s_wv[w] > bv) || (s_wv[w] == bv && s_wi[w] < bi);
        if (b) { bv = s_wv[w]; bi = s_wi[w]; bt = s_wt[w]; }
      }
      s_ov[round] = bv; s_oi[round] = bi; s_wtid = bt;
    }
    __syncthreads();
    if (tid == s_wtid) ++h;
    __syncthreads();
  }
  if (tid < TOPK) {
    cand_iou[r * TOPK + tid] = s_ov[tid];
    cand_idx[r * TOPK + tid] = s_oi[tid];
  }
}

// Kernel B: the serial buggy-JV matcher, ONE wave (64 threads), ~1 round per target + chains.
__global__ void match_kernel(const float4* __restrict__ pbox, const float4* __restrict__ tboxg,
                             const float* __restrict__ cand_iou, const int* __restrict__ cand_idx,
                             double* __restrict__ v, int* __restrict__ p, int* __restrict__ uep,
                             int* __restrict__ intouch, int* __restrict__ touched,
                             int* __restrict__ pairs, int M, int NROWS) {
  const int lane = threadIdx.x;  // 64 threads = 1 wave
  __shared__ double s_u[136];
  __shared__ int    s_ulist[1024];
  __shared__ float4 s_tb[132];
  __shared__ int s_row, s_i0, s_cnt, s_nt, s_done;

  for (int k = lane; k <= NROWS; k += 64) s_u[k] = 0.0;
  for (int k = lane; k < NROWS; k += 64) s_tb[k] = tboxg[k];
  if (lane == 0) {
    s_row = 1; s_i0 = 1; s_cnt = 1; s_nt = 0; s_done = 0;
    s_ulist[0] = 0;
    p[0] = 1;                        // reference: p[0] = i at row start
  }
  __syncthreads();

  for (int iter = 0; iter < 200000; ++iter) {
    if (s_done) break;
    const int row = s_row, i0 = s_i0, cnt = s_cnt, nt = s_nt;
    const float4 tb = s_tb[i0 - 1];
    const float area_t = (tb.z - tb.x) * (tb.w - tb.y);
    const double u_i0 = s_u[i0];

    // candidates: top-64 of row i0  ∪  all columns with v != 0, minus visited-this-row
    double best = 1e300; int bj = 0x7fffffff;
    const int ncand = TOPK + nt;
    for (int k = lane; k < ncand; k += 64) {
      int j; float io;
      if (k < TOPK) {
        j = cand_idx[(i0 - 1) * TOPK + k];
        if (j > M) continue;                       // sentinel
        io = cand_iou[(i0 - 1) * TOPK + k];
      } else {
        j = touched[k - TOPK];
        io = iou_f32(pbox[j - 1], tb, area_t);
      }
      if (uep[j] == row) continue;                 // used this search
      double cur = (-(double)io - u_i0) - v[j];    // exact reference op order (f64)
      if (cur < best || (cur == best && j < bj)) { best = cur; bj = j; }
    }
    for (int off = 32; off; off >>= 1) {
      double ov = __shfl_down(best, off); int oj = __shfl_down(bj, off);
      if (ov < best || (ov == best && oj < bj)) { best = ov; bj = oj; }
    }
    const double delta = __shfl(best, 0);
    const int j1 = __shfl(bj, 0);

    // u[p[used]] += delta ; v[used] -= delta  (owners distinct -> parallel exact)
    for (int k = lane; k < cnt; k += 64) {
      int uc = s_ulist[k];
      int owner = p[uc];                           // p[0] == current row (maintained)
      s_u[owner] += delta;
      if (uc) {
        v[uc] -= delta;
        if (intouch[uc] == 0) {                    // at most one new per iteration
          intouch[uc] = 1;
          touched[nt] = uc;
          s_nt = nt + 1;
        }
      }
    }
    if (lane == 0) {
      int pj1 = p[j1];
      if (pj1 == 0) {
        p[j1] = row;                               // augment (way==0 collapses)
        pairs[row - 1] = j1 - 1;
        if (row == NROWS) s_done = 1;
        else { s_row = row + 1; s_i0 = row + 1; s_cnt = 1; p[0] = row + 1; }
      } else {
        uep[j1] = row;                             // mark visited this row
        s_ulist[cnt] = j1; s_cnt = cnt + 1;
        s_i0 = pj1;                                // chain to owner row
      }
    }
    __syncthreads();
  }
}

__global__ void loss_kernel(const float4* __restrict__ pbox, const float* __restrict__ confs,
                            const float4* __restrict__ tbox, const int* __restrict__ tlab,
                            const int* __restrict__ pairs, float* __restrict__ out,
                            int NROWS, int C) {
  const int tid = threadIdx.x;
  __shared__ float s_reg[NTHR_A];
  __shared__ float s_cls[NTHR_A];
  __shared__ int   s_acc[NTHR_A];
  float reg = 0.0f, cls = 0.0f; int acc = 0;
  if (tid < NROWS) {
    int pred = pairs[tid];
    float4 pb = pbox[pred];
    float4 tb = tbox[tid];
    float d0 = pb.x - tb.x, d1 = pb.y - tb.y, d2 = pb.z - tb.z, d3 = pb.w - tb.w;
    float a0 = fabsf(d0), a1 = fabsf(d1), a2 = fabsf(d2), a3 = fabsf(d3);
    float s = 0.0f;
    s += (a0 < 1.0f) ? 0.5f * d0 * d0 : a0 - 0.5f;
    s += (a1 < 1.0f) ? 0.5f * d1 * d1 : a1 - 0.5f;
    s += (a2 < 1.0f) ? 0.5f * d2 * d2 : a2 - 0.5f;
    s += (a3 < 1.0f) ? 0.5f * d3 * d3 : a3 - 0.5f;
    reg = s * 0.25f;

    const float* lg = confs + (long long)pred * C;
    float mx = lg[0]; int am = 0;
    for (int k = 1; k < C; ++k) { float x = lg[k]; if (x > mx) { mx = x; am = k; } }
    double se = 0.0;
    for (int k = 0; k < C; ++k) se += exp((double)(lg[k] - mx));
    int lab = tlab[tid];
    double logp = (double)(lg[lab] - mx) - log(se);
    cls = (float)(-logp);
    acc = (am == lab) ? 1 : 0;
  }
  s_reg[tid] = reg; s_cls[tid] = cls; s_acc[tid] = acc;
  __syncthreads();
  for (int s2 = NTHR_A / 2; s2 > 0; s2 >>= 1) {
    if (tid < s2) {
      s_reg[tid] += s_reg[tid + s2];
      s_cls[tid] += s_cls[tid + s2];
      s_acc[tid] += s_acc[tid + s2];
    }
    __syncthreads();
  }
  if (tid == 0) {
    out[0] = s_reg[0] + s_cls[0];
    out[1] = (float)s_acc[0];
  }
}

extern "C" void kernel_launch(void* const* d_in, const int* in_sizes, int n_in,
                              void* d_out, int out_size, void* d_ws, size_t ws_size,
                              hipStream_t stream) {
  const float4* pbox  = (const float4*)d_in[0];
  const float*  confs = (const float*)d_in[1];
  const float4* tbox  = (const float4*)d_in[2];
  const int*    tlab  = (const int*)d_in[3];

  int N = in_sizes[0] / 4;          // 100000 predictions
  int C = in_sizes[1] / N;          // 81 classes
  int NROWS = in_sizes[2] / 4;      // 128 targets
  int M = N;                        // columns = predictions

  char* w = (char*)d_ws;
  auto alloc = [&](size_t sz) { char* r = w; w += (sz + 255) & ~(size_t)255; return r; };
  double* v        = (double*)alloc((size_t)(M + 2) * sizeof(double));
  int*    p        = (int*)   alloc((size_t)(M + 2) * sizeof(int));
  int*    uep      = (int*)   alloc((size_t)(M + 2) * sizeof(int));
  int*    intouch  = (int*)   alloc((size_t)(M + 2) * sizeof(int));
  float*  cand_iou = (float*) alloc((size_t)NROWS * TOPK * sizeof(float));
  int*    cand_idx = (int*)   alloc((size_t)NROWS * TOPK * sizeof(int));
  int*    touched  = (int*)   alloc((size_t)8192 * sizeof(int));
  int*    pairs    = (int*)   alloc((size_t)(NROWS + 8) * sizeof(int));

  select_kernel<<<NROWS, NTHR_A, 0, stream>>>(pbox, tbox, v, p, uep, intouch,
                                              cand_iou, cand_idx, M, NROWS);
  match_kernel<<<1, 64, 0, stream>>>(pbox, tbox, cand_iou, cand_idx,
                                     v, p, uep, intouch, touched, pairs, M, NROWS);
  loss_kernel<<<1, NTHR_A, 0, stream>>>(pbox, confs, tbox, tlab, pairs,
                                        (float*)d_out, NROWS, C);
}

// Round 3
// 392.307 us; speedup vs baseline: 6.9298x; 2.7987x over previous
//
#include <hip/hip_runtime.h>
#include <cstdint>
#include <cstddef>

typedef unsigned long long u64;
typedef unsigned int u32;

#define SLICES 16
#define WAVES_A 4
#define POOLCAP 1600          // max columns per wave-slice: ceil(6250/256)=25 iters * 64 lanes
#define HCAP 1024
#define HMASK (HCAP - 1)
#define TCAP 512
#define UCAP 512

// IoU exactly as reference _box_iou, all f32 IEEE ops (bit-exact per rounds 1-2, absmax=0).
__device__ __forceinline__ float iou_f32(float4 p, float4 t, float area_t) {
  float area1 = (p.z - p.x) * (p.w - p.y);
  float ltx = fmaxf(p.x, t.x);
  float lty = fmaxf(p.y, t.y);
  float rbx = fminf(p.z, t.z);
  float rby = fminf(p.w, t.w);
  float wx = fmaxf(rbx - ltx, 0.0f);
  float wy = fmaxf(rby - lty, 0.0f);
  float inter = wx * wy;
  return inter / (area1 + area_t - inter);
}

__device__ __forceinline__ int hprobe(const u32* h_col, u32 colp1) {
  int h = (int)((colp1 * 2654435761u) >> 22) & HMASK;
  for (;;) {
    u32 c = h_col[h];
    if (c == 0u || c == colp1) return h;
    h = (h + 1) & HMASK;
  }
}

// Kernel A: per (slice,row) block, per-wave compact (positives + first-64 zeros) then
// 64 rounds of wave-argmax over u64 keys -> sorted top-64 per wave-slice.
__global__ __launch_bounds__(256) void select_kernel(const float4* __restrict__ pbox,
                                                     const float4* __restrict__ tbox,
                                                     u64* __restrict__ lists,
                                                     int M, int NROWS) {
  __shared__ u64 s_pool[WAVES_A][POOLCAP];
  const int tid = threadIdx.x;
  const int w = tid >> 6, lane = tid & 63;
  const int slice = blockIdx.x, row = blockIdx.y;
  const int sw = (M + SLICES - 1) / SLICES;
  const int base = slice * sw;
  const int send = min(base + sw, M);
  const float4 tb = tbox[row];
  const float area_t = (tb.z - tb.x) * (tb.w - tb.y);
  const u64 lower = (1ull << lane) - 1ull;

  int wcount = 0, zcount = 0;
  const int iters = (sw + 255) / 256;
  for (int it = 0; it < iters; ++it) {
    int col = base + it * 256 + tid;
    bool inr = col < send;
    float io = -1.0f;
    if (inr) io = iou_f32(pbox[col], tb, area_t);
    u64 key = ((u64)__float_as_uint(io) << 32) | (u64)(0xFFFFFFFFu - (u32)col);
    bool pos = inr && (io > 0.0f);
    u64 pmask = __ballot(pos);
    if (pos) s_pool[w][wcount + (int)__popcll(pmask & lower)] = key;
    wcount += (int)__popcll(pmask);
    if (zcount < 64) {               // zero-iou fill candidates, ascending column order
      bool z = inr && (io == 0.0f);
      u64 zmask = __ballot(z);
      int zoff = (int)__popcll(zmask & lower);
      int take = 64 - zcount;
      if (z && zoff < take) s_pool[w][wcount + zoff] = key;
      int zn = (int)__popcll(zmask); if (zn > take) zn = take;
      wcount += zn; zcount += zn;
    }
  }
  __syncthreads();

  u64 out = 0;
  for (int r = 0; r < 64; ++r) {
    u64 mk = 0; int mt = -1;
    for (int t = lane; t < wcount; t += 64) {
      u64 k2 = s_pool[w][t];
      if (k2 > mk) { mk = k2; mt = t; }
    }
    u64 pre = mk;
    for (int off = 32; off; off >>= 1) {
      u64 o = __shfl_xor(mk, off);
      if (o > mk) mk = o;
    }
    if (lane == r) out = mk;
    if (pre == mk && mt >= 0 && mk != 0) s_pool[w][mt] = 0;  // unique owner tombstones
    __syncthreads();
  }
  int listid = (row * SLICES + slice) * WAVES_A + w;
  lists[(size_t)listid * 64 + lane] = out;
}

// Kernel B: merge 64 sorted lists of 64 -> exact top-64 per row (head-advance rounds).
__global__ __launch_bounds__(64) void merge_kernel(const u64* __restrict__ lists,
                                                   u64* __restrict__ cand, int NROWS) {
  const int lane = threadIdx.x;
  const int row = blockIdx.x;
  const u64* Lb = lists + ((size_t)row * 64 + lane) * 64;
  u64 key = Lb[0];
  u64 pf  = Lb[1];
  int nu = 2;
  u64 out = 0;
  for (int r = 0; r < 64; ++r) {
    u64 mk = key; int ml = lane;
    for (int off = 32; off; off >>= 1) {
      u64 o = __shfl_xor(mk, off);
      int ol = __shfl_xor(ml, off);
      if (o > mk) { mk = o; ml = ol; }
    }
    if (lane == r) out = mk;
    if (lane == ml) {
      key = pf;
      pf = (nu < 64) ? Lb[nu] : 0;
      ++nu;
    }
  }
  cand[(size_t)row * 64 + lane] = out;
}

// Kernel C: the serial buggy-JV matcher, 1 wave, all mutable state in LDS hash.
__global__ __launch_bounds__(64) void match_kernel(const float4* __restrict__ pbox,
                                                   const float4* __restrict__ tboxg,
                                                   const u64* __restrict__ cand,
                                                   int* __restrict__ pairs,
                                                   int M, int NROWS) {
  const int lane = threadIdx.x;
  __shared__ double s_u[132];
  __shared__ u32    h_col[HCAP];
  __shared__ int    h_owner[HCAP];
  __shared__ int    h_vis[HCAP];
  __shared__ int    h_tix[HCAP];
  __shared__ double h_v[HCAP];
  __shared__ float4 s_tb[132];
  __shared__ float4 s_pb[TCAP];
  __shared__ u32    touch_col[TCAP];
  __shared__ u32    used_col[UCAP];
  __shared__ int    used_owner[UCAP];
  __shared__ int    s_nt;

  for (int i = lane; i < HCAP; i += 64) {
    h_col[i] = 0; h_owner[i] = 0; h_vis[i] = 0; h_tix[i] = -1; h_v[i] = 0.0;
  }
  for (int i = lane; i <= NROWS; i += 64) s_u[i] = 0.0;
  for (int i = lane; i < NROWS; i += 64) s_tb[i] = tboxg[i];
  if (lane == 0) { s_nt = 0; used_col[0] = 0xFFFFFFFFu; used_owner[0] = 1; }
  __syncthreads();

  int row = 1, i0 = 1, cnt = 1;
  u64 ck = cand[lane];                           // current row's candidate (lane k holds entry k)
  u64 pk = (NROWS >= 2) ? cand[64 + lane] : 0;   // speculative prefetch of row+1

  for (int guard = 0; guard < 100000; ++guard) {
    const int nt = s_nt;
    const double u_i0 = s_u[i0];
    const float4 tbi = s_tb[i0 - 1];
    const float area_t = (tbi.z - tbi.x) * (tbi.w - tbi.y);

    double best = 1e300; int bc = 0x7fffffff;
    for (int k = lane; k < 64 + nt; k += 64) {
      float io; int c; double v; int vis;
      if (k < 64) {                // register candidate (k == lane on first pass)
        u64 key = ck;
        if (key == 0) continue;
        io = __uint_as_float((u32)(key >> 32));
        c = (int)(0xFFFFFFFFu - (u32)key);
        int h = hprobe(h_col, (u32)(c + 1));
        bool present = (h_col[h] == (u32)(c + 1));
        vis = present ? h_vis[h] : 0;
        v   = present ? h_v[h]  : 0.0;
      } else {                     // touched column (v != 0 somewhere in history)
        c = (int)touch_col[k - 64];
        int h = hprobe(h_col, (u32)(c + 1));
        vis = h_vis[h];
        v   = h_v[h];
        io  = iou_f32(s_pb[h_tix[h]], tbi, area_t);
      }
      if (vis == row) continue;    // visited during this row's search
      double cur = (-(double)io - u_i0) - v;   // exact reference op order (f64)
      if (cur < best || (cur == best && c < bc)) { best = cur; bc = c; }
    }
    for (int off = 32; off; off >>= 1) {
      double ov = __shfl_xor(best, off);
      int    oc = __shfl_xor(bc, off);
      if (ov < best || (ov == best && oc < bc)) { best = ov; bc = oc; }
    }
    const double delta = best;
    const int jc = bc;             // 0-based winner column

    // u[p[used]] += delta ; v[used] -= delta   (owners distinct -> parallel exact)
    for (int k = lane; k < cnt; k += 64) {
      u32 co = used_col[k];
      int ow = used_owner[k];
      s_u[ow] += delta;
      if (co != 0xFFFFFFFFu) {
        int h = hprobe(h_col, co + 1);
        h_v[h] -= delta;
        if (h_tix[h] < 0) {        // at most one new touched per iteration
          h_tix[h] = nt;
          touch_col[nt] = co;
          s_pb[nt] = pbox[co];
          s_nt = nt + 1;
        }
      }
    }
    int hj = hprobe(h_col, (u32)(jc + 1));
    int owned = (h_col[hj] == (u32)(jc + 1)) ? h_owner[hj] : 0;
    __syncthreads();

    if (owned == 0) {
      // augment: assign jc to row (way==0 collapses augmentation to one write)
      if (lane == 0) {
        h_col[hj] = (u32)(jc + 1);
        h_owner[hj] = row;         // h_vis/h_tix/h_v hold init values (fresh column)
        pairs[row - 1] = jc;
      }
      if (row == NROWS) break;
      ++row; i0 = row; cnt = 1;
      if (lane == 0) { used_col[0] = 0xFFFFFFFFu; used_owner[0] = row; }
      ck = pk;                                            // prefetched, usually arrived
      pk = (row < NROWS) ? cand[(size_t)row * 64 + lane] : 0;
    } else {
      // chain to owner row
      if (lane == 0) {
        h_vis[hj] = row;
        used_col[cnt] = (u32)jc;
        used_owner[cnt] = owned;
      }
      ++cnt;
      i0 = owned;
      ck = cand[(size_t)(i0 - 1) * 64 + lane];            // cold load (chains are rare)
    }
    __syncthreads();
  }
}

__global__ __launch_bounds__(256) void loss_kernel(const float4* __restrict__ pbox,
                                                   const float* __restrict__ confs,
                                                   const float4* __restrict__ tbox,
                                                   const int* __restrict__ tlab,
                                                   const int* __restrict__ pairs,
                                                   float* __restrict__ out,
                                                   int NROWS, int C) {
  const int tid = threadIdx.x;
  __shared__ float s_reg[256];
  __shared__ float s_cls[256];
  __shared__ int   s_acc[256];
  float reg = 0.0f, cls = 0.0f; int acc = 0;
  if (tid < NROWS) {
    int pred = pairs[tid];
    float4 pb = pbox[pred];
    float4 tb = tbox[tid];
    float d0 = pb.x - tb.x, d1 = pb.y - tb.y, d2 = pb.z - tb.z, d3 = pb.w - tb.w;
    float a0 = fabsf(d0), a1 = fabsf(d1), a2 = fabsf(d2), a3 = fabsf(d3);
    float s = 0.0f;
    s += (a0 < 1.0f) ? 0.5f * d0 * d0 : a0 - 0.5f;
    s += (a1 < 1.0f) ? 0.5f * d1 * d1 : a1 - 0.5f;
    s += (a2 < 1.0f) ? 0.5f * d2 * d2 : a2 - 0.5f;
    s += (a3 < 1.0f) ? 0.5f * d3 * d3 : a3 - 0.5f;
    reg = s * 0.25f;

    const float* lg = confs + (long long)pred * C;
    float mx = lg[0]; int am = 0;
    for (int k = 1; k < C; ++k) { float x = lg[k]; if (x > mx) { mx = x; am = k; } }
    double se = 0.0;
    for (int k = 0; k < C; ++k) se += exp((double)(lg[k] - mx));
    int lab = tlab[tid];
    double logp = (double)(lg[lab] - mx) - log(se);
    cls = (float)(-logp);
    acc = (am == lab) ? 1 : 0;
  }
  s_reg[tid] = reg; s_cls[tid] = cls; s_acc[tid] = acc;
  __syncthreads();
  for (int s2 = 128; s2 > 0; s2 >>= 1) {
    if (tid < s2) {
      s_reg[tid] += s_reg[tid + s2];
      s_cls[tid] += s_cls[tid + s2];
      s_acc[tid] += s_acc[tid + s2];
    }
    __syncthreads();
  }
  if (tid == 0) {
    out[0] = s_reg[0] + s_cls[0];
    out[1] = (float)s_acc[0];
  }
}

extern "C" void kernel_launch(void* const* d_in, const int* in_sizes, int n_in,
                              void* d_out, int out_size, void* d_ws, size_t ws_size,
                              hipStream_t stream) {
  const float4* pbox  = (const float4*)d_in[0];
  const float*  confs = (const float*)d_in[1];
  const float4* tbox  = (const float4*)d_in[2];
  const int*    tlab  = (const int*)d_in[3];

  int N = in_sizes[0] / 4;          // 100000 predictions (columns)
  int C = in_sizes[1] / N;          // 81 classes
  int NROWS = in_sizes[2] / 4;      // 128 targets (rows)
  int M = N;

  char* w = (char*)d_ws;
  auto alloc = [&](size_t sz) { char* r = w; w += (sz + 255) & ~(size_t)255; return r; };
  u64* lists = (u64*)alloc((size_t)NROWS * 64 * 64 * sizeof(u64));   // 4 MB
  u64* cnd   = (u64*)alloc((size_t)NROWS * 64 * sizeof(u64));        // 64 KB
  int* pairs = (int*)alloc((size_t)(NROWS + 8) * sizeof(int));

  select_kernel<<<dim3(SLICES, NROWS), 256, 0, stream>>>(pbox, tbox, lists, M, NROWS);
  merge_kernel<<<NROWS, 64, 0, stream>>>(lists, cnd, NROWS);
  match_kernel<<<1, 64, 0, stream>>>(pbox, tbox, cnd, pairs, M, NROWS);
  loss_kernel<<<1, 256, 0, stream>>>(pbox, confs, tbox, tlab, pairs,
                                     (float*)d_out, NROWS, C);
}

// Round 4
// 286.182 us; speedup vs baseline: 9.4995x; 1.3708x over previous
//
#include <hip/hip_runtime.h>
#include <cstdint>
#include <cstddef>

typedef unsigned long long u64;
typedef unsigned int u32;

#define HCAP 1024
#define HMASK (HCAP - 1)
#define CAND 256            // per-row candidate capacity (4 slots x 64 lanes)
#define TCAP 512
#define UCAP 512
#define NBINS 2048
#define SEL_THR 1024

// IoU exactly as reference _box_iou, all f32 IEEE ops (bit-exact, absmax=0 rounds 1-3).
__device__ __forceinline__ float iou_f32(float4 p, float4 t, float area_t) {
  float area1 = (p.z - p.x) * (p.w - p.y);
  float ltx = fmaxf(p.x, t.x);
  float lty = fmaxf(p.y, t.y);
  float rbx = fminf(p.z, t.z);
  float rby = fminf(p.w, t.w);
  float wx = fmaxf(rbx - ltx, 0.0f);
  float wy = fmaxf(rby - lty, 0.0f);
  float inter = wx * wy;
  return inter / (area1 + area_t - inter);
}

// Kernel A: per-row candidate pool via histogram threshold.
// Pool = all cols with iou>0 and bin(iou) >= B where B = highest bin with
// cum-from-top >= 64. Pool SET is a superset of the exact top-64 by iou.
__global__ __launch_bounds__(SEL_THR) void select_kernel(const float4* __restrict__ pbox,
                                                         const float4* __restrict__ tbox,
                                                         u64* __restrict__ cand,
                                                         int* __restrict__ ncand,
                                                         int M, int NROWS) {
  __shared__ u32 s_hist[NBINS];
  __shared__ int s_red[SEL_THR / 64];
  __shared__ u64 s_pool[CAND];
  __shared__ int s_n, s_B, s_np;
  const int tid = threadIdx.x;
  const int row = blockIdx.x;
  const float4 tb = tbox[row];
  const float area_t = (tb.z - tb.x) * (tb.w - tb.y);

  for (int b = tid; b < NBINS; b += SEL_THR) s_hist[b] = 0;
  if (tid == 0) { s_n = 0; }
  __syncthreads();

  int mypos = 0;
  for (int j = tid; j < M; j += SEL_THR) {
    float io = iou_f32(pbox[j], tb, area_t);
    if (io > 0.0f) { atomicAdd(&s_hist[__float_as_uint(io) >> 19], 1u); ++mypos; }
  }
  for (int off = 32; off; off >>= 1) mypos += __shfl_down(mypos, off);
  if ((tid & 63) == 0) s_red[tid >> 6] = mypos;
  __syncthreads();
  if (tid == 0) {
    int t = 0;
    for (int w2 = 0; w2 < SEL_THR / 64; ++w2) t += s_red[w2];
    s_np = t;
  }
  __syncthreads();
  const int np = s_np;

  if (tid < 64) {                       // wave 0: descending scan for threshold bin B
    int B = 0;
    if (np >= 64) {
      int R = 0; bool found = false;
      for (int ch = NBINS / 64 - 1; ch >= 0 && !found; --ch) {
        int cum = (int)s_hist[ch * 64 + tid];
        for (int off = 1; off < 64; off <<= 1) {
          int o = __shfl_down(cum, off);
          if (tid + off < 64) cum += o;
        }
        int chunksum = __shfl(cum, 0);
        if (R + chunksum >= 64) {
          u64 m = __ballot(R + cum >= 64);
          int l = 63 - __clzll(m);
          B = ch * 64 + l;
          found = true;
        } else R += chunksum;
      }
    }
    if (tid == 0) s_B = B;
  }
  __syncthreads();
  const int B = s_B;

  for (int j = tid; j < M; j += SEL_THR) {
    float io = iou_f32(pbox[j], tb, area_t);
    if (io > 0.0f && (int)(__float_as_uint(io) >> 19) >= B) {
      int pos = atomicAdd(&s_n, 1);
      if (pos < CAND) s_pool[pos] = ((u64)__float_as_uint(io) << 32) | (u32)j;
    }
  }
  __syncthreads();

  if (np < 64 && tid < 64) {            // rare zero-fill: first (64-np) zero-iou cols ascending
    int need = 64 - np, got = 0;
    int base_n = s_n;
    for (int base = 0; base < M && got < need; base += 64) {
      int j = base + tid;
      float io = (j < M) ? iou_f32(pbox[j], tb, area_t) : -1.0f;
      bool z = (j < M) && (io == 0.0f);
      u64 zm = __ballot(z);
      int rank = (int)__popcll(zm & ((1ull << tid) - 1ull));
      if (z && rank < need - got) {
        int pos = base_n + got + rank;
        if (pos < CAND) s_pool[pos] = (u64)(u32)j;   // io bits = 0
      }
      int zn = (int)__popcll(zm);
      if (zn > need - got) zn = need - got;
      got += zn;
    }
    if (tid == 0) s_n = base_n + got;
  }
  __syncthreads();

  int n = s_n; if (n > CAND) n = CAND;
  if (tid < n && tid < CAND) cand[(size_t)row * CAND + tid] = s_pool[tid];
  if (tid == 0) ncand[row] = n;
}

__device__ __forceinline__ u64 map_cost(double cur) {
  u64 b = (u64)__double_as_longlong(cur);
  if (b == 0x8000000000000000ull) b = 0;                 // canonicalize -0 -> +0 (bit-level)
  return (b >> 63) ? ~b : (b | 0x8000000000000000ull);   // order-exact total map
}
__device__ __forceinline__ double unmap_cost(u64 m) {
  u64 b = (m >> 63) ? (m ^ 0x8000000000000000ull) : ~m;
  return __longlong_as_double((long long)b);
}

// Kernel B: the serial buggy-JV matcher, 1 wave, register-resident fast path.
// Invariant: never-won columns have v=0 and are never 'visited' mid-search,
// so fresh candidates need no per-iteration LDS reads.
__global__ __launch_bounds__(64) void match_kernel(const float4* __restrict__ pbox,
                                                   const float4* __restrict__ tboxg,
                                                   const u64* __restrict__ cand,
                                                   const int* __restrict__ ncand,
                                                   int* __restrict__ pairs,
                                                   int M, int NROWS) {
  const int lane = threadIdx.x;
  __shared__ u32    h_col[HCAP];
  __shared__ int    h_owner[HCAP];
  __shared__ int    h_vis[HCAP];
  __shared__ int    h_tin[HCAP];
  __shared__ double h_v[HCAP];
  __shared__ int    t_hix[TCAP];
  __shared__ int    t_colA[TCAP];
  __shared__ float4 t_box[TCAP];
  __shared__ int    u_hixL[UCAP];
  __shared__ float4 s_tb[128];
  __shared__ float  s_ta[128];
  __shared__ int    s_nc[128];

  for (int i = lane; i < HCAP; i += 64) h_col[i] = 0;
  for (int i = lane; i < NROWS; i += 64) {
    float4 t = tboxg[i];
    s_tb[i] = t;
    s_ta[i] = (t.z - t.x) * (t.w - t.y);
    s_nc[i] = ncand[i];
  }
  __builtin_amdgcn_wave_barrier();
  __syncthreads();   // one wave: cheap; ensures LDS init visible before probes

  int c[4]; float io[4]; int hx[4]; u64 pf[4];
  double u_a = 0.0, u_b = 0.0;      // u[lane+1], u[lane+65]
  int f_a = 0, f_b = 0;             // in-chain flags for my u rows
  double u_i0 = 0.0;
  int row = 1, i0 = 1, cnt = 0, nt_u = 0;

#pragma unroll
  for (int s = 0; s < 4; ++s) pf[s] = cand[(s << 6) + lane];

  auto load_row = [&](int r) {
    int nc = s_nc[r - 1];
#pragma unroll
    for (int s = 0; s < 4; ++s) {
      int idx = (s << 6) + lane;
      if (idx < nc) {
        u64 k = pf[s];
        c[s] = (int)(u32)k;
        io[s] = __uint_as_float((u32)(k >> 32));
      } else c[s] = -1;
    }
    int nr = (r < NROWS) ? r + 1 : r;
#pragma unroll
    for (int s = 0; s < 4; ++s) pf[s] = cand[(size_t)(nr - 1) * CAND + (s << 6) + lane];
#pragma unroll
    for (int s = 0; s < 4; ++s) {
      hx[s] = -1;
      if (c[s] >= 0) {
        int h = (int)(((u32)(c[s] + 1) * 2654435761u) >> 22) & HMASK;
        for (;;) {
          u32 cc = h_col[h];
          if (cc == (u32)(c[s] + 1)) { hx[s] = h; break; }
          if (cc == 0) break;
          h = (h + 1) & HMASK;
        }
      }
    }
    f_a = (lane == ((r - 1) & 63)) && (((r - 1) >> 6) == 0);
    f_b = (lane == ((r - 1) & 63)) && (((r - 1) >> 6) == 1);
    u_i0 = 0.0;                       // u[row] == 0 at its own search start (proven)
    i0 = r; cnt = 0;
  };

  load_row(1);

  for (int guard = 0; guard < 4000; ++guard) {
    const int ntv = nt_u;
    float4 tbi; float ati = 0.0f;
    if (ntv > 0) { tbi = s_tb[i0 - 1]; ati = s_ta[i0 - 1]; }

    u64 bkey = ~0ull; int bcol = 0x7fffffff; int bow = 0; int bhx = -1;
#pragma unroll
    for (int s = 0; s < 4; ++s) {
      if (c[s] < 0) continue;
      bool hr = hx[s] >= 0;
      int vis = hr ? h_vis[hx[s]] : 0;
      if (hr && vis == row) continue;
      double v = hr ? h_v[hx[s]] : 0.0;
      int ow = hr ? h_owner[hx[s]] : 0;
      double cur = (-(double)io[s] - u_i0) - v;     // exact reference f64 op order
      u64 mk = map_cost(cur);
      bool t = (mk < bkey) || (mk == bkey && c[s] < bcol);
      if (t) { bkey = mk; bcol = c[s]; bow = ow; bhx = hx[s]; }
    }
    for (int k = lane; k < ntv; k += 64) {          // touched cols not in my slots
      int hxk = t_hix[k];
      if (h_vis[hxk] == row) continue;
      float io2 = iou_f32(t_box[k], tbi, ati);
      double cur = (-(double)io2 - u_i0) - h_v[hxk];
      u64 mk = map_cost(cur);
      int cc = t_colA[k];
      bool t = (mk < bkey) || (mk == bkey && cc < bcol);
      if (t) { bkey = mk; bcol = cc; bow = h_owner[hxk]; bhx = hxk; }
    }

    u64 rkey = bkey; int rcol = bcol;
    for (int off = 32; off; off >>= 1) {
      u64 ok = (u64)__shfl_xor((long long)rkey, off);
      int oc = __shfl_xor(rcol, off);
      bool t = (ok < rkey) || (ok == rkey && oc < rcol);
      if (t) { rkey = ok; rcol = oc; }
    }
    const int jc = rcol;                                  // winner col (0-based)
    u64 wm = __ballot(bkey == rkey && bcol == rcol);
    const int L = (int)__ffsll((long long)wm) - 1;
    const int ow_jc = __shfl(bow, L);
    const int hix_jc = __shfl(bhx, L);
    const double delta = unmap_cost(rkey);

    // reference: u[p[used]] += delta ; v[used] -= delta  (used = pre-append set)
    if (f_a) u_a += delta;
    if (f_b) u_b += delta;
    u_i0 += delta;
    for (int k = lane; k < cnt; k += 64) h_v[u_hixL[k]] -= delta;
    __builtin_amdgcn_wave_barrier();

    if (ow_jc == 0) {
      // augment: way==0 collapses to single assignment p[jc]=row
      if (lane == L) {
        int h2 = hix_jc;
        if (h2 < 0) {
          h2 = (int)(((u32)(jc + 1) * 2654435761u) >> 22) & HMASK;
          while (h_col[h2] != 0) h2 = (h2 + 1) & HMASK;
          h_col[h2] = (u32)(jc + 1);
          h_v[h2] = 0.0; h_vis[h2] = 0; h_tin[h2] = 0;
        }
        h_owner[h2] = row;
        pairs[row - 1] = jc;
      }
      __builtin_amdgcn_wave_barrier();
      if (row == NROWS) break;
      ++row;
      load_row(row);
    } else {
      int tin0 = 0;
      if (lane == L) {
        h_vis[hix_jc] = row;
        u_hixL[cnt] = hix_jc;
        tin0 = (h_tin[hix_jc] == 0) ? 1 : 0;
        if (tin0) {
          h_tin[hix_jc] = 1;
          t_hix[nt_u] = hix_jc;
          t_colA[nt_u] = jc;
          t_box[nt_u] = pbox[jc];
        }
      }
      nt_u += __shfl(tin0, L);
      ++cnt;
      int o = ow_jc - 1;
      if (lane == (o & 63)) { if ((o >> 6) == 0) f_a = 1; else f_b = 1; }
      i0 = ow_jc;
      double ra = __shfl(u_a, o & 63);
      double rb = __shfl(u_b, o & 63);
      u_i0 = ((o >> 6) == 0) ? ra : rb;
    }
    __builtin_amdgcn_wave_barrier();
  }
}

__global__ __launch_bounds__(256) void loss_kernel(const float4* __restrict__ pbox,
                                                   const float* __restrict__ confs,
                                                   const float4* __restrict__ tbox,
                                                   const int* __restrict__ tlab,
                                                   const int* __restrict__ pairs,
                                                   float* __restrict__ out,
                                                   int NROWS, int C) {
  const int tid = threadIdx.x;
  __shared__ float s_reg[256];
  __shared__ float s_cls[256];
  __shared__ int   s_acc[256];
  float reg = 0.0f, cls = 0.0f; int acc = 0;
  if (tid < NROWS) {
    int pred = pairs[tid];
    float4 pb = pbox[pred];
    float4 tb = tbox[tid];
    float d0 = pb.x - tb.x, d1 = pb.y - tb.y, d2 = pb.z - tb.z, d3 = pb.w - tb.w;
    float a0 = fabsf(d0), a1 = fabsf(d1), a2 = fabsf(d2), a3 = fabsf(d3);
    float s = 0.0f;
    s += (a0 < 1.0f) ? 0.5f * d0 * d0 : a0 - 0.5f;
    s += (a1 < 1.0f) ? 0.5f * d1 * d1 : a1 - 0.5f;
    s += (a2 < 1.0f) ? 0.5f * d2 * d2 : a2 - 0.5f;
    s += (a3 < 1.0f) ? 0.5f * d3 * d3 : a3 - 0.5f;
    reg = s * 0.25f;

    const float* lg = confs + (long long)pred * C;
    float mx = lg[0]; int am = 0;
    for (int k = 1; k < C; ++k) { float x = lg[k]; if (x > mx) { mx = x; am = k; } }
    double se = 0.0;
    for (int k = 0; k < C; ++k) se += exp((double)(lg[k] - mx));
    int lab = tlab[tid];
    double logp = (double)(lg[lab] - mx) - log(se);
    cls = (float)(-logp);
    acc = (am == lab) ? 1 : 0;
  }
  s_reg[tid] = reg; s_cls[tid] = cls; s_acc[tid] = acc;
  __syncthreads();
  for (int s2 = 128; s2 > 0; s2 >>= 1) {
    if (tid < s2) {
      s_reg[tid] += s_reg[tid + s2];
      s_cls[tid] += s_cls[tid + s2];
      s_acc[tid] += s_acc[tid + s2];
    }
    __syncthreads();
  }
  if (tid == 0) {
    out[0] = s_reg[0] + s_cls[0];
    out[1] = (float)s_acc[0];
  }
}

extern "C" void kernel_launch(void* const* d_in, const int* in_sizes, int n_in,
                              void* d_out, int out_size, void* d_ws, size_t ws_size,
                              hipStream_t stream) {
  const float4* pbox  = (const float4*)d_in[0];
  const float*  confs = (const float*)d_in[1];
  const float4* tbox  = (const float4*)d_in[2];
  const int*    tlab  = (const int*)d_in[3];

  int N = in_sizes[0] / 4;          // 100000 predictions (columns)
  int C = in_sizes[1] / N;          // 81 classes
  int NROWS = in_sizes[2] / 4;      // 128 targets (rows), <=128 supported
  int M = N;

  char* w = (char*)d_ws;
  auto alloc = [&](size_t sz) { char* r = w; w += (sz + 255) & ~(size_t)255; return r; };
  u64* cand  = (u64*)alloc((size_t)NROWS * CAND * sizeof(u64));
  int* ncand = (int*)alloc((size_t)(NROWS + 8) * sizeof(int));
  int* pairs = (int*)alloc((size_t)(NROWS + 8) * sizeof(int));

  select_kernel<<<NROWS, SEL_THR, 0, stream>>>(pbox, tbox, cand, ncand, M, NROWS);
  match_kernel<<<1, 64, 0, stream>>>(pbox, tbox, cand, ncand, pairs, M, NROWS);
  loss_kernel<<<1, 256, 0, stream>>>(pbox, confs, tbox, tlab, pairs,
                                     (float*)d_out, NROWS, C);
}